// Round 3
// baseline (1151.263 us; speedup 1.0000x reference)
//
#include <hip/hip_runtime.h>
#include <hip/hip_bf16.h>
#include <cstdint>
#include <cstddef>

#define N_NODES 50000
#define N_EDGES 600000
#define DF 128
#define N_ETYPES 4
#define N_STEPS 5
#define SCAN_NB 196    // ceil(50000/256)
#define GRU_GRIDX 192
#define GRU_NT ((N_NODES + 31) / 32)   // 1563

typedef _Float16 f16x8 __attribute__((ext_vector_type(8)));
typedef _Float16 f16x4 __attribute__((ext_vector_type(4)));
typedef _Float16 f16x2 __attribute__((ext_vector_type(2)));
typedef float f32x4 __attribute__((ext_vector_type(4)));

__device__ __forceinline__ float sigmoid_fast(float x) {
    return 1.0f / (1.0f + __expf(-x));
}
__device__ __forceinline__ float tanh_fast(float x) {
    return 1.0f - 2.0f / (__expf(2.0f * x) + 1.0f);
}
// load 8 consecutive fp32 and round to f16x8 (MFMA A-frag helper)
__device__ __forceinline__ f16x8 cvt8(const float* p) {
    float4 u = *(const float4*)p;
    float4 v = *(const float4*)(p + 4);
    f16x8 r;
    r[0] = (_Float16)u.x; r[1] = (_Float16)u.y;
    r[2] = (_Float16)u.z; r[3] = (_Float16)u.w;
    r[4] = (_Float16)v.x; r[5] = (_Float16)v.y;
    r[6] = (_Float16)v.z; r[7] = (_Float16)v.w;
    return r;
}

// ---------------- setup kernels (once per launch) ----------------

// Wl -> f16; build concatenated GRU B matrix Bc[g][c][k]: k<128 -> wih, else whh
__global__ __launch_bounds__(256) void k_cvt_w(
    const float* __restrict__ Wl, const float* __restrict__ wih,
    const float* __restrict__ whh, _Float16* __restrict__ Wl_h,
    _Float16* __restrict__ Bc) {
    int i = blockIdx.x * 256 + threadIdx.x;          // grid covers 98304
    if (i < N_ETYPES * DF * DF) Wl_h[i] = (_Float16)Wl[i];
    int row = i >> 8;                                // 0..383 = g*128 + c
    int k = i & 255;
    float v = (k < 128) ? wih[row * 128 + k] : whh[row * 128 + (k - 128)];
    Bc[i] = (_Float16)v;
}

__global__ __launch_bounds__(256) void k_hist(
    const int* __restrict__ dst, int* __restrict__ deg, int E) {
    int i = blockIdx.x * 256 + threadIdx.x;
    if (i < E) atomicAdd(&deg[dst[i]], 1);
}

// hierarchical exclusive scan over deg[0..N)
__global__ __launch_bounds__(256) void k_part(
    const int* __restrict__ deg, int* __restrict__ part, int N) {
    __shared__ int s[256];
    int t = threadIdx.x, i = blockIdx.x * 256 + t;
    s[t] = (i < N) ? deg[i] : 0;
    __syncthreads();
    for (int off = 128; off > 0; off >>= 1) {
        if (t < off) s[t] += s[t + off];
        __syncthreads();
    }
    if (t == 0) part[blockIdx.x] = s[0];
}

__global__ __launch_bounds__(256) void k_scan1(int* __restrict__ part, int nb) {
    __shared__ int s[256];
    int t = threadIdx.x;
    int v = (t < nb) ? part[t] : 0;
    s[t] = v;
    __syncthreads();
    for (int off = 1; off < 256; off <<= 1) {
        int u = (t >= off) ? s[t - off] : 0;
        __syncthreads();
        s[t] += u;
        __syncthreads();
    }
    if (t < nb) part[t] = s[t] - v;
}

__global__ __launch_bounds__(256) void k_row(
    const int* __restrict__ deg, const int* __restrict__ part,
    int* __restrict__ row_start, int* __restrict__ cursor, int N) {
    __shared__ int s[256];
    int t = threadIdx.x, i = blockIdx.x * 256 + t;
    int d = (i < N) ? deg[i] : 0;
    s[t] = d;
    __syncthreads();
    for (int off = 1; off < 256; off <<= 1) {
        int u = (t >= off) ? s[t - off] : 0;
        __syncthreads();
        s[t] += u;
        __syncthreads();
    }
    int rs = part[blockIdx.x] + s[t] - d;
    if (i < N) {
        row_start[i] = rs;
        cursor[i] = rs;
        if (i == N - 1) row_start[N] = rs + d;
    }
}

__global__ __launch_bounds__(256) void k_fill(
    const int* __restrict__ src, const int* __restrict__ dst,
    const int* __restrict__ ety, int* __restrict__ cursor,
    int* __restrict__ csr, int E) {
    int i = blockIdx.x * 256 + threadIdx.x;
    if (i < E) {
        int slot = atomicAdd(&cursor[dst[i]], 1);
        csr[slot] = src[i] | ((ety[i] - 1) << 16);   // src < 65536, et in 0..3
    }
}

// ---------------- per-step kernels ----------------

// t[k][n][f] = sum_d h[n,d] * W[k][f,d] + b_lin[k][f]   (fp32 h in, f16 out)
__global__ __launch_bounds__(256) void k_lin(
    const float* __restrict__ h, const _Float16* __restrict__ Wl,
    const float* __restrict__ b_lin, _Float16* __restrict__ t_out, int N) {
    const int wave = threadIdx.x >> 6, lane = threadIdx.x & 63;
    const int col = lane & 15, quad = lane >> 4;
    const int r0 = blockIdx.x * 64 + wave * 16;
    int arow = r0 + col; if (arow >= N) arow = N - 1;
    f16x8 a[4];
    const float* hp = h + (size_t)arow * DF + quad * 8;
#pragma unroll
    for (int kt = 0; kt < 4; kt++) a[kt] = cvt8(hp + kt * 32);
#pragma unroll
    for (int ktype = 0; ktype < N_ETYPES; ktype++) {
        const _Float16* W = Wl + (size_t)ktype * DF * DF;
        _Float16* tk = t_out + (size_t)ktype * N * DF;
#pragma unroll
        for (int ft = 0; ft < 8; ft++) {
            f32x4 acc = {0.f, 0.f, 0.f, 0.f};
            const _Float16* wrow = W + (size_t)(ft * 16 + col) * DF + quad * 8;
#pragma unroll
            for (int kt = 0; kt < 4; kt++)
                acc = __builtin_amdgcn_mfma_f32_16x16x32_f16(
                    a[kt], *(const f16x8*)(wrow + kt * 32), acc, 0, 0, 0);
            float bias = b_lin[ktype * DF + ft * 16 + col];
#pragma unroll
            for (int i = 0; i < 4; i++) {
                int row = r0 + quad * 4 + i;
                if (row < N)
                    tk[(size_t)row * DF + ft * 16 + col] = (_Float16)(acc[i] + bias);
            }
        }
    }
}

// a[n][:] = sum over incoming edges of t[et][src][:]  -> f16
__global__ __launch_bounds__(256) void k_agg(
    const _Float16* __restrict__ t, const int* __restrict__ row_start,
    const int* __restrict__ csr, _Float16* __restrict__ ah, int N) {
    const int wave = threadIdx.x >> 6, lane = threadIdx.x & 63;
    const int n = blockIdx.x * 4 + wave;             // grid = N/4 exactly
    const int beg = row_start[n], end = row_start[n + 1];
    float s0 = 0.f, s1 = 0.f, s2 = 0.f, s3 = 0.f;
    float s4 = 0.f, s5 = 0.f, s6 = 0.f, s7 = 0.f;
    int e = beg;
    for (; e + 3 < end; e += 4) {
        int p0 = csr[e], p1 = csr[e + 1], p2 = csr[e + 2], p3 = csr[e + 3];
        f16x2 v0 = *(const f16x2*)(t + ((((size_t)(p0 >> 16)) * N + (p0 & 0xFFFF)) << 7) + lane * 2);
        f16x2 v1 = *(const f16x2*)(t + ((((size_t)(p1 >> 16)) * N + (p1 & 0xFFFF)) << 7) + lane * 2);
        f16x2 v2 = *(const f16x2*)(t + ((((size_t)(p2 >> 16)) * N + (p2 & 0xFFFF)) << 7) + lane * 2);
        f16x2 v3 = *(const f16x2*)(t + ((((size_t)(p3 >> 16)) * N + (p3 & 0xFFFF)) << 7) + lane * 2);
        s0 += (float)v0.x; s1 += (float)v0.y;
        s2 += (float)v1.x; s3 += (float)v1.y;
        s4 += (float)v2.x; s5 += (float)v2.y;
        s6 += (float)v3.x; s7 += (float)v3.y;
    }
    for (; e < end; e++) {
        int p0 = csr[e];
        f16x2 v0 = *(const f16x2*)(t + ((((size_t)(p0 >> 16)) * N + (p0 & 0xFFFF)) << 7) + lane * 2);
        s0 += (float)v0.x; s1 += (float)v0.y;
    }
    f16x2 o;
    o.x = (_Float16)(s0 + s2 + s4 + s6);
    o.y = (_Float16)(s1 + s3 + s5 + s7);
    *(f16x2*)(ah + ((size_t)n << 7) + lane * 2) = o;
}

// GRU with concat-K (K=256, A=[a|h]) and LDS-resident weights.
// blockIdx.y = col-group (32 of 128 h-cols); block stages 3x32 B-rows (50.7 KB),
// then grid-strides over 32-row tasks. r,z: one fused accumulator each;
// n-gate: kt 0..3 -> i_n acc, kt 4..7 -> h_n acc (separate, since r scales h_n only).
__global__ __launch_bounds__(256, 3) void k_gru(
    const _Float16* __restrict__ ah, const float* __restrict__ h_in,
    const _Float16* __restrict__ Bc, const float* __restrict__ b_ih,
    const float* __restrict__ b_hh, float* __restrict__ h_out, int N) {
    __shared__ _Float16 Bs[96 * 264];                // 264 = 256 + 8 pad (bank spread)
    const int wave = threadIdx.x >> 6, lane = threadIdx.x & 63;
    const int col16 = lane & 15, quad = lane >> 4;
    const int cg = blockIdx.y;

    // stage B rows [g*128 + cg*32 .. +32) for g=0..2
    for (int i = threadIdx.x; i < 96 * 32; i += 256) {
        int lrow = i >> 5;
        int o = (i & 31) << 3;                       // f16 offset in row
        int g = lrow >> 5, r32 = lrow & 31;
        const _Float16* gp = Bc + (((size_t)(g * 128 + cg * 32 + r32)) << 8) + o;
        *(f16x8*)&Bs[lrow * 264 + o] = *(const f16x8*)gp;
    }
    __syncthreads();

    float bR[2], bZ[2], bIN[2], bHN[2];
#pragma unroll
    for (int t = 0; t < 2; t++) {
        int c = cg * 32 + t * 16 + col16;
        bR[t] = b_ih[c] + b_hh[c];
        bZ[t] = b_ih[128 + c] + b_hh[128 + c];
        bIN[t] = b_ih[256 + c];
        bHN[t] = b_hh[256 + c];
    }

    const int gw = blockIdx.x * 4 + wave;
    for (int task = gw; task < GRU_NT; task += GRU_GRIDX * 4) {
        const int r0 = task * 32;
        f16x8 A[2][8];                               // [sub-tile][kt]; kt<4 = a, kt>=4 = h
#pragma unroll
        for (int sub = 0; sub < 2; sub++) {
            int ar = r0 + sub * 16 + col16;
            if (ar >= N) ar = N - 1;
            const _Float16* ap = ah + ((size_t)ar << 7) + quad * 8;
#pragma unroll
            for (int kt = 0; kt < 4; kt++)
                A[sub][kt] = *(const f16x8*)(ap + kt * 32);
            const float* hp = h_in + ((size_t)ar << 7) + quad * 8;
#pragma unroll
            for (int kt = 0; kt < 4; kt++)
                A[sub][4 + kt] = cvt8(hp + kt * 32);
        }
        f32x4 acc[4][2][2];                          // [set r,z,in,hn][tile][sub]
#pragma unroll
        for (int s = 0; s < 4; s++)
#pragma unroll
            for (int t = 0; t < 2; t++)
#pragma unroll
                for (int sub = 0; sub < 2; sub++)
                    acc[s][t][sub] = (f32x4){0.f, 0.f, 0.f, 0.f};
#pragma unroll
        for (int t = 0; t < 2; t++)
#pragma unroll
            for (int g = 0; g < 3; g++)
#pragma unroll
                for (int kt = 0; kt < 8; kt++) {
                    f16x8 b = *(const f16x8*)&Bs[(g * 32 + t * 16 + col16) * 264 + quad * 8 + kt * 32];
                    const int set = (g < 2) ? g : (kt < 4 ? 2 : 3);
#pragma unroll
                    for (int sub = 0; sub < 2; sub++)
                        acc[set][t][sub] = __builtin_amdgcn_mfma_f32_16x16x32_f16(
                            A[sub][kt], b, acc[set][t][sub], 0, 0, 0);
                }
#pragma unroll
        for (int sub = 0; sub < 2; sub++)
#pragma unroll
            for (int t = 0; t < 2; t++) {
                int c = cg * 32 + t * 16 + col16;
#pragma unroll
                for (int i = 0; i < 4; i++) {
                    int row = r0 + sub * 16 + quad * 4 + i;
                    if (row < N) {
                        float r = sigmoid_fast(acc[0][t][sub][i] + bR[t]);
                        float z = sigmoid_fast(acc[1][t][sub][i] + bZ[t]);
                        float nn = tanh_fast(acc[2][t][sub][i] + bIN[t] +
                                             r * (acc[3][t][sub][i] + bHN[t]));
                        size_t idx = ((size_t)row << 7) + c;
                        h_out[idx] = (1.f - z) * nn + z * h_in[idx];
                    }
                }
            }
    }
}

// ---------------- launch ----------------

extern "C" void kernel_launch(void* const* d_in, const int* in_sizes, int n_in,
                              void* d_out, int out_size, void* d_ws, size_t ws_size,
                              hipStream_t stream) {
    const float* h0    = (const float*)d_in[0];
    const int*   src   = (const int*)d_in[1];
    const int*   dst   = (const int*)d_in[2];
    const int*   ety   = (const int*)d_in[3];
    const float* W_lin = (const float*)d_in[4];
    const float* b_lin = (const float*)d_in[5];
    const float* w_ih  = (const float*)d_in[6];
    const float* w_hh  = (const float*)d_in[7];
    const float* b_ih  = (const float*)d_in[8];
    const float* b_hh  = (const float*)d_in[9];
    float* hout = (float*)d_out;

    char* p = (char*)d_ws;
    auto alloc = [&](size_t bytes) -> char* {
        char* r = p;
        p += (bytes + 255) & ~(size_t)255;
        return r;
    };
    float*    h_ws   = (float*)alloc((size_t)N_NODES * DF * 4);
    _Float16* a_half = (_Float16*)alloc((size_t)N_NODES * DF * 2);
    _Float16* t_half = (_Float16*)alloc((size_t)N_ETYPES * N_NODES * DF * 2);
    _Float16* Wl_h   = (_Float16*)alloc((size_t)N_ETYPES * DF * DF * 2);
    _Float16* Bc     = (_Float16*)alloc((size_t)3 * DF * 2 * DF * 2);   // [3][128][256] f16
    int* deg       = (int*)alloc((size_t)N_NODES * 4);
    int* row_start = (int*)alloc((size_t)(N_NODES + 1) * 4);
    int* cursor    = (int*)alloc((size_t)N_NODES * 4);
    int* csr       = (int*)alloc((size_t)N_EDGES * 4);
    int* part      = (int*)alloc((size_t)SCAN_NB * 4);

    hipMemsetAsync(deg, 0, (size_t)N_NODES * 4, stream);
    k_cvt_w<<<384, 256, 0, stream>>>(W_lin, w_ih, w_hh, Wl_h, Bc);
    k_hist<<<(N_EDGES + 255) / 256, 256, 0, stream>>>(dst, deg, N_EDGES);
    k_part<<<SCAN_NB, 256, 0, stream>>>(deg, part, N_NODES);
    k_scan1<<<1, 256, 0, stream>>>(part, SCAN_NB);
    k_row<<<SCAN_NB, 256, 0, stream>>>(deg, part, row_start, cursor, N_NODES);
    k_fill<<<(N_EDGES + 255) / 256, 256, 0, stream>>>(src, dst, ety, cursor, csr, N_EDGES);

    // fp32 h ping-pong: writes land in d_out on steps 0,2,4 (final in d_out);
    // in != out every step so k_gru's cross-column A reads never race its writes.
    const float* cur = h0;
    const int nb = (N_NODES + 63) / 64;              // 782
    for (int s = 0; s < N_STEPS; s++) {
        k_lin<<<nb, 256, 0, stream>>>(cur, Wl_h, b_lin, t_half, N_NODES);
        k_agg<<<N_NODES / 4, 256, 0, stream>>>(t_half, row_start, csr, a_half, N_NODES);
        float* nxt = (s & 1) ? h_ws : hout;
        k_gru<<<dim3(GRU_GRIDX, 4), 256, 0, stream>>>(a_half, cur, Bc, b_ih, b_hh, nxt, N_NODES);
        cur = nxt;
    }
}